// Round 4
// baseline (362.097 us; speedup 1.0000x reference)
//
#include <hip/hip_runtime.h>
#include <stdint.h>

#define NTOK 2048
#define DIM  1024
#define HID  2048
#define NEXP 8
#define CAP  4224   // 4096 assignments + 128 tile-overflow pad
#define RB   256    // router blocks inside fused pre-kernel
#define CB   1024   // convert blocks inside fused pre-kernel

typedef __attribute__((ext_vector_type(8))) short short8;
typedef __attribute__((ext_vector_type(4))) float floatx4;
typedef __attribute__((ext_vector_type(4))) unsigned short ushortx4;

static __device__ __forceinline__ unsigned short f2bf(float f) {
  uint32_t u = __builtin_bit_cast(uint32_t, f);
  u += 0x7fffu + ((u >> 16) & 1u);   // round-to-nearest-even
  return (unsigned short)(u >> 16);
}

// ---- fused: router (blocks 0..RB-1) + weight fp32->bf16 convert (blocks RB..)
// NO __shared__ anywhere in this kernel: a 32KB static LDS array would cap
// occupancy at 5 blocks/CU for ALL blocks (measured r3: 34% occ, 1.6 TB/s).
// Router reads Wr straight from global (32KB, L2/L3-hot, shared by all blocks).
// Convert: 8 outstanding 16B loads per lane to cover ~900cyc HBM latency.
__global__ void __launch_bounds__(256) pre_kernel(const float* __restrict__ x,
                                                  const float* __restrict__ Wr,
                                                  const float* __restrict__ Wfc,
                                                  const float* __restrict__ Wpr,
                                                  unsigned short* __restrict__ bfc,
                                                  unsigned short* __restrict__ bpr,
                                                  int* __restrict__ ctrl,
                                                  int* __restrict__ experts,
                                                  float* __restrict__ wts) {
  if (blockIdx.x >= RB) {
    // ---------------- weight conversion ----------------
    const size_t nth = (size_t)CB * 256;                    // 262,144 threads
    size_t base = (size_t)(blockIdx.x - RB) * 256 + threadIdx.x;
    // N4 per tensor = 4,194,304 -> 16 iterations per thread per tensor
#pragma unroll
    for (int ph = 0; ph < 2; ph++) {
      floatx4 v[8];
#pragma unroll
      for (int j = 0; j < 8; j++)
        v[j] = ((const floatx4*)Wfc)[base + (size_t)(ph * 8 + j) * nth];
#pragma unroll
      for (int j = 0; j < 8; j++) {
        ushortx4 b;
        b.x = f2bf(v[j].x); b.y = f2bf(v[j].y); b.z = f2bf(v[j].z); b.w = f2bf(v[j].w);
        ((ushortx4*)bfc)[base + (size_t)(ph * 8 + j) * nth] = b;
      }
    }
#pragma unroll
    for (int ph = 0; ph < 2; ph++) {
      floatx4 v[8];
#pragma unroll
      for (int j = 0; j < 8; j++)
        v[j] = ((const floatx4*)Wpr)[base + (size_t)(ph * 8 + j) * nth];
#pragma unroll
      for (int j = 0; j < 8; j++) {
        ushortx4 b;
        b.x = f2bf(v[j].x); b.y = f2bf(v[j].y); b.z = f2bf(v[j].z); b.w = f2bf(v[j].w);
        ((ushortx4*)bpr)[base + (size_t)(ph * 8 + j) * nth] = b;
      }
    }
    return;
  }

  // ---------------- router (fp32 exact) ----------------
  const int wave = threadIdx.x >> 6;
  const int lane = threadIdx.x & 63;

#pragma unroll
  for (int j = 0; j < 2; j++) {
    int t = blockIdx.x * 8 + wave * 2 + j;
    const float* xr = x + (size_t)t * DIM;
    float acc[NEXP];
#pragma unroll
    for (int e = 0; e < NEXP; e++) acc[e] = 0.f;
#pragma unroll
    for (int i = 0; i < 4; i++) {
      floatx4 v = ((const floatx4*)xr)[i * 64 + lane];
      int idx = (i * 64 + lane) * 4;
#pragma unroll
      for (int e = 0; e < NEXP; e++) {
        floatx4 w = *(const floatx4*)&Wr[e * DIM + idx];
        acc[e] += v.x * w.x + v.y * w.y + v.z * w.z + v.w * w.w;
      }
    }
#pragma unroll
    for (int e = 0; e < NEXP; e++) {
#pragma unroll
      for (int off = 32; off > 0; off >>= 1) acc[e] += __shfl_down(acc[e], off);
    }
    if (lane == 0) {
      float mx = acc[0];
      for (int e = 1; e < NEXP; e++) mx = fmaxf(mx, acc[e]);
      float p[NEXP], s = 0.f;
      for (int e = 0; e < NEXP; e++) { p[e] = expf(acc[e] - mx); s += p[e]; }
      float inv = 1.f / s;
      for (int e = 0; e < NEXP; e++) p[e] *= inv;
      int i0 = 0; float p0 = p[0];
      for (int e = 1; e < NEXP; e++) if (p[e] > p0) { p0 = p[e]; i0 = e; }   // ties: lowest idx
      int i1 = -1; float p1 = -1.f;
      for (int e = 0; e < NEXP; e++) if (e != i0 && p[e] > p1) { p1 = p[e]; i1 = e; }
      float rn = 1.f / (p0 + p1 + 1e-8f);
      experts[2 * t] = i0; experts[2 * t + 1] = i1;
      wts[2 * t] = p0 * rn; wts[2 * t + 1] = p1 * rn;
      atomicAdd(&ctrl[i0], 1);
      atomicAdd(&ctrl[i1], 1);
    }
  }
}

// ---------------- scan: bases + cursors from counts (8 values) ---------------
__global__ void scan_kernel(int* __restrict__ ctrl) {
  if (threadIdx.x == 0) {
    int s = 0;
    for (int e = 0; e < NEXP; e++) { ctrl[8 + e] = s; ctrl[16 + e] = s; s += ctrl[e]; }
  }
}

// ---------------- gather: compact token rows into Xe (bf16) ------------------
__global__ void __launch_bounds__(256) gather_kernel(const float* __restrict__ x,
                                                     int* __restrict__ ctrl,
                                                     const int* __restrict__ experts,
                                                     int* __restrict__ pos,
                                                     unsigned short* __restrict__ Xe) {
  int t = blockIdx.x;
  __shared__ int ps[2];
  if (threadIdx.x == 0) {
    int e0 = experts[2 * t], e1 = experts[2 * t + 1];
    int p0 = atomicAdd(&ctrl[16 + e0], 1);
    int p1 = atomicAdd(&ctrl[16 + e1], 1);
    pos[2 * t] = p0; pos[2 * t + 1] = p1;
    ps[0] = p0; ps[1] = p1;
  }
  __syncthreads();
  int p0 = ps[0], p1 = ps[1];
  int i = threadIdx.x;                         // handles floats 4i..4i+3
  floatx4 v = ((const floatx4*)(x + (size_t)t * DIM))[i];
  ushortx4 b;
  b.x = f2bf(v.x); b.y = f2bf(v.y); b.z = f2bf(v.z); b.w = f2bf(v.w);
  *(ushortx4*)(Xe + (size_t)p0 * DIM + 4 * i) = b;
  *(ushortx4*)(Xe + (size_t)p1 * DIM + 4 * i) = b;
}

// ---------------- m97-style bf16 GEMM, per-expert, B^T layout ----------------
// A: [CAP x K] bf16 (rows base..), B: [NEXP*N x K] bf16. C = A @ B^T.
// EPI=0: relu(C)^2 -> bf16 (He).  EPI=1: fp32 store (Ye).
template <int K, int N, int EPI>
__global__ void __launch_bounds__(256) gemm_kernel(const unsigned short* __restrict__ A,
                                                   const unsigned short* __restrict__ B,
                                                   unsigned short* __restrict__ Cbf,
                                                   float* __restrict__ Cf,
                                                   const int* __restrict__ ctrl) {
  const int e = blockIdx.z;
  const int cnt = ctrl[e];
  const int m0 = blockIdx.y * 128;
  if (m0 >= cnt) return;
  const int base = ctrl[8 + e];
  const int n0 = blockIdx.x * 128;

  __shared__ __align__(16) unsigned short ldsA[128 * 64];
  __shared__ __align__(16) unsigned short ldsB[128 * 64];

  const int tid = threadIdx.x;
  const int lane = tid & 63;
  const int wave = tid >> 6;
  const int wm = wave & 1, wn = wave >> 1;

  const unsigned short* Ae = A + (size_t)(base + m0) * K;
  const unsigned short* Be = B + ((size_t)e * N + n0) * (size_t)K;

  const int rsub = lane >> 3;   // row within 8-row chunk
  const int sg = lane & 7;      // stored 16B group (swizzled)

  floatx4 acc[4][4];
  floatx4 zero = {0.f, 0.f, 0.f, 0.f};
#pragma unroll
  for (int i = 0; i < 4; i++)
#pragma unroll
    for (int j = 0; j < 4; j++) acc[i][j] = zero;

  for (int k0 = 0; k0 < K; k0 += 64) {
#pragma unroll
    for (int j = 0; j < 4; j++) {
      int c = wave * 4 + j;
      int rc = c * 8 + rsub;
      int g = sg ^ (rc & 7);
      const unsigned short* ga = Ae + (size_t)rc * K + k0 + g * 8;
      const unsigned short* gb = Be + (size_t)rc * K + k0 + g * 8;
      __builtin_amdgcn_global_load_lds((const __attribute__((address_space(1))) unsigned int*)ga,
                                       (__attribute__((address_space(3))) unsigned int*)&ldsA[c * 512],
                                       16, 0, 0);
      __builtin_amdgcn_global_load_lds((const __attribute__((address_space(1))) unsigned int*)gb,
                                       (__attribute__((address_space(3))) unsigned int*)&ldsB[c * 512],
                                       16, 0, 0);
    }
    __builtin_amdgcn_s_waitcnt(0x0f70);  // vmcnt(0)
    __syncthreads();

#pragma unroll
    for (int kk = 0; kk < 2; kk++) {
      int q = lane >> 4;
      int gk = kk * 4 + q;
      short8 af[4], bfr[4];
#pragma unroll
      for (int mi = 0; mi < 4; mi++) {
        int row = wm * 64 + mi * 16 + (lane & 15);
        af[mi] = *(const short8*)&ldsA[row * 64 + (gk ^ (row & 7)) * 8];
      }
#pragma unroll
      for (int ni = 0; ni < 4; ni++) {
        int row = wn * 64 + ni * 16 + (lane & 15);
        bfr[ni] = *(const short8*)&ldsB[row * 64 + (gk ^ (row & 7)) * 8];
      }
#pragma unroll
      for (int mi = 0; mi < 4; mi++)
#pragma unroll
        for (int ni = 0; ni < 4; ni++)
          acc[mi][ni] = __builtin_amdgcn_mfma_f32_16x16x32_bf16(af[mi], bfr[ni], acc[mi][ni], 0, 0, 0);
    }
    __syncthreads();
  }

  // epilogue: D row=(lane>>4)*4+reg, col=lane&15
  // expert segments are packed back-to-back: mask stores past cnt.
  const int lm = lane >> 4;
  const int ln = lane & 15;
#pragma unroll
  for (int mi = 0; mi < 4; mi++) {
#pragma unroll
    for (int ni = 0; ni < 4; ni++) {
#pragma unroll
      for (int r = 0; r < 4; r++) {
        int row = m0 + wm * 64 + mi * 16 + lm * 4 + r;   // local row in expert segment
        if (row < cnt) {
          int col = n0 + wn * 64 + ni * 16 + ln;
          float v = acc[mi][ni][r];
          if (EPI == 0) {
            v = fmaxf(v, 0.f);
            v = v * v;
            Cbf[(size_t)(base + row) * N + col] = f2bf(v);
          } else {
            Cf[(size_t)(base + row) * N + col] = v;
          }
        }
      }
    }
  }
}

// ---------------- combine: out[t] = w0*Ye[p0] + w1*Ye[p1] --------------------
__global__ void __launch_bounds__(256) combine_kernel(const float* __restrict__ Ye,
                                                      const int* __restrict__ pos,
                                                      const float* __restrict__ wts,
                                                      float* __restrict__ out) {
  int t = blockIdx.x;
  int i = threadIdx.x;
  int p0 = pos[2 * t], p1 = pos[2 * t + 1];
  float w0 = wts[2 * t], w1 = wts[2 * t + 1];
  floatx4 y0 = ((const floatx4*)(Ye + (size_t)p0 * DIM))[i];
  floatx4 y1 = ((const floatx4*)(Ye + (size_t)p1 * DIM))[i];
  floatx4 o = y0 * w0 + y1 * w1;
  ((floatx4*)(out + (size_t)t * DIM))[i] = o;
  if (t == 0 && i == 0) out[(size_t)NTOK * DIM] = 0.f;  // aux_loss = 0
}

extern "C" void kernel_launch(void* const* d_in, const int* in_sizes, int n_in,
                              void* d_out, int out_size, void* d_ws, size_t ws_size,
                              hipStream_t stream) {
  const float* x   = (const float*)d_in[0];
  const float* Wr  = (const float*)d_in[1];
  const float* Wfc = (const float*)d_in[2];
  const float* Wpr = (const float*)d_in[3];
  float* out = (float*)d_out;
  char* ws = (char*)d_ws;

  const size_t WELEMS = (size_t)NEXP * HID * DIM;  // 16,777,216 per weight tensor

  int*   ctrl    = (int*)ws;                          // counts[8] bases[8] cursor[8]
  int*   experts = (int*)(ws + 128);                  // int2 per token
  int*   pos     = (int*)(ws + 128 + 16384);          // int2 per token
  float* wts     = (float*)(ws + 128 + 32768);        // float2 per token
  unsigned short* Wfcb = (unsigned short*)(ws + 65536);
  unsigned short* Wprb = Wfcb + WELEMS;
  unsigned short* Xe   = Wprb + WELEMS;               // [CAP x DIM] bf16
  unsigned short* He   = Xe + (size_t)CAP * DIM;      // [CAP x HID] bf16
  float*          Ye   = (float*)(He + (size_t)CAP * HID);  // [CAP x DIM] f32

  hipMemsetAsync(ws, 0, 128, stream);  // zero counts/bases/cursors

  pre_kernel<<<RB + CB, 256, 0, stream>>>(x, Wr, Wfc, Wpr, Wfcb, Wprb, ctrl, experts, wts);
  scan_kernel<<<1, 64, 0, stream>>>(ctrl);
  gather_kernel<<<NTOK, 256, 0, stream>>>(x, ctrl, experts, pos, Xe);

  gemm_kernel<DIM, HID, 0><<<dim3(HID / 128, 16, NEXP), 256, 0, stream>>>(Xe, Wfcb, He, nullptr, ctrl);
  gemm_kernel<HID, DIM, 1><<<dim3(DIM / 128, 16, NEXP), 256, 0, stream>>>(He, Wprb, nullptr, Ye, ctrl);

  combine_kernel<<<NTOK, 256, 0, stream>>>(Ye, pos, wts, out);
}

// Round 5
// 351.243 us; speedup vs baseline: 1.0309x; 1.0309x over previous
//
#include <hip/hip_runtime.h>
#include <stdint.h>

#define NTOK 2048
#define DIM  1024
#define HID  2048
#define NEXP 8
#define CAP  4224   // 4096 assignments + 128 tile-overflow pad
#define RB   256    // router blocks inside fused pre-kernel
#define CPAIRS (NEXP * HID * DIM / 8)   // 8-float chunks per weight tensor = 2,097,152
#define CBT  (CPAIRS / 256)             // convert blocks per tensor = 8192

typedef __attribute__((ext_vector_type(8))) short short8;
typedef __attribute__((ext_vector_type(4))) float floatx4;
typedef __attribute__((ext_vector_type(4))) unsigned short ushortx4;
typedef __attribute__((ext_vector_type(8))) unsigned short ushortx8;

static __device__ __forceinline__ unsigned short f2bf(float f) {
  uint32_t u = __builtin_bit_cast(uint32_t, f);
  u += 0x7fffu + ((u >> 16) & 1u);   // round-to-nearest-even
  return (unsigned short)(u >> 16);
}

// ---- fused: router (blocks 0..RB-1) + weight fp32->bf16 convert (blocks RB..)
// Convert uses the r2-proven streaming shape: HUGE grid, ONE short dependency
// chain per thread (2 float4 loads -> 1 16B bf16 store). Latency is hidden by
// block turnover (m13 regime), not in-wave batching — r3/r4 showed batched
// low-block-count variants plateau at ~2 TB/s effective.
__global__ void __launch_bounds__(256) pre_kernel(const float* __restrict__ x,
                                                  const float* __restrict__ Wr,
                                                  const float* __restrict__ Wfc,
                                                  const float* __restrict__ Wpr,
                                                  unsigned short* __restrict__ bfc,
                                                  unsigned short* __restrict__ bpr,
                                                  int* __restrict__ ctrl,
                                                  int* __restrict__ experts,
                                                  float* __restrict__ wts) {
  if (blockIdx.x >= RB) {
    int bid2 = blockIdx.x - RB;
    const float* src; unsigned short* dst;
    size_t idx;
    if (bid2 < CBT) { src = Wfc; dst = bfc; idx = (size_t)bid2 * 256 + threadIdx.x; }
    else            { src = Wpr; dst = bpr; idx = (size_t)(bid2 - CBT) * 256 + threadIdx.x; }
    floatx4 a = ((const floatx4*)src)[2 * idx];
    floatx4 b = ((const floatx4*)src)[2 * idx + 1];
    ushortx8 o;
    o[0] = f2bf(a.x); o[1] = f2bf(a.y); o[2] = f2bf(a.z); o[3] = f2bf(a.w);
    o[4] = f2bf(b.x); o[5] = f2bf(b.y); o[6] = f2bf(b.z); o[7] = f2bf(b.w);
    ((ushortx8*)dst)[idx] = o;
    return;
  }

  // ---------------- router (fp32 exact) ----------------
  const int wave = threadIdx.x >> 6;
  const int lane = threadIdx.x & 63;

#pragma unroll
  for (int j = 0; j < 2; j++) {
    int t = blockIdx.x * 8 + wave * 2 + j;
    const float* xr = x + (size_t)t * DIM;
    float acc[NEXP];
#pragma unroll
    for (int e = 0; e < NEXP; e++) acc[e] = 0.f;
#pragma unroll
    for (int i = 0; i < 4; i++) {
      floatx4 v = ((const floatx4*)xr)[i * 64 + lane];
      int idx = (i * 64 + lane) * 4;
#pragma unroll
      for (int e = 0; e < NEXP; e++) {
        floatx4 w = *(const floatx4*)&Wr[e * DIM + idx];
        acc[e] += v.x * w.x + v.y * w.y + v.z * w.z + v.w * w.w;
      }
    }
#pragma unroll
    for (int e = 0; e < NEXP; e++) {
#pragma unroll
      for (int off = 32; off > 0; off >>= 1) acc[e] += __shfl_down(acc[e], off);
    }
    if (lane == 0) {
      float mx = acc[0];
      for (int e = 1; e < NEXP; e++) mx = fmaxf(mx, acc[e]);
      float p[NEXP], s = 0.f;
      for (int e = 0; e < NEXP; e++) { p[e] = expf(acc[e] - mx); s += p[e]; }
      float inv = 1.f / s;
      for (int e = 0; e < NEXP; e++) p[e] *= inv;
      int i0 = 0; float p0 = p[0];
      for (int e = 1; e < NEXP; e++) if (p[e] > p0) { p0 = p[e]; i0 = e; }   // ties: lowest idx
      int i1 = -1; float p1 = -1.f;
      for (int e = 0; e < NEXP; e++) if (e != i0 && p[e] > p1) { p1 = p[e]; i1 = e; }
      float rn = 1.f / (p0 + p1 + 1e-8f);
      experts[2 * t] = i0; experts[2 * t + 1] = i1;
      wts[2 * t] = p0 * rn; wts[2 * t + 1] = p1 * rn;
      atomicAdd(&ctrl[i0], 1);
      atomicAdd(&ctrl[i1], 1);
    }
  }
}

// ---------------- scan: bases + cursors from counts (8 values) ---------------
__global__ void scan_kernel(int* __restrict__ ctrl) {
  if (threadIdx.x == 0) {
    int s = 0;
    for (int e = 0; e < NEXP; e++) { ctrl[8 + e] = s; ctrl[16 + e] = s; s += ctrl[e]; }
  }
}

// ---------------- gather: compact token rows into Xe (bf16) ------------------
__global__ void __launch_bounds__(256) gather_kernel(const float* __restrict__ x,
                                                     int* __restrict__ ctrl,
                                                     const int* __restrict__ experts,
                                                     int* __restrict__ pos,
                                                     unsigned short* __restrict__ Xe) {
  int t = blockIdx.x;
  __shared__ int ps[2];
  if (threadIdx.x == 0) {
    int e0 = experts[2 * t], e1 = experts[2 * t + 1];
    int p0 = atomicAdd(&ctrl[16 + e0], 1);
    int p1 = atomicAdd(&ctrl[16 + e1], 1);
    pos[2 * t] = p0; pos[2 * t + 1] = p1;
    ps[0] = p0; ps[1] = p1;
  }
  __syncthreads();
  int p0 = ps[0], p1 = ps[1];
  int i = threadIdx.x;                         // handles floats 4i..4i+3
  floatx4 v = ((const floatx4*)(x + (size_t)t * DIM))[i];
  ushortx4 b;
  b.x = f2bf(v.x); b.y = f2bf(v.y); b.z = f2bf(v.z); b.w = f2bf(v.w);
  *(ushortx4*)(Xe + (size_t)p0 * DIM + 4 * i) = b;
  *(ushortx4*)(Xe + (size_t)p1 * DIM + 4 * i) = b;
}

// ---------------- m97-style bf16 GEMM, per-expert, B^T layout ----------------
// A: [CAP x K] bf16 (rows base..), B: [NEXP*N x K] bf16. C = A @ B^T.
// EPI=0: relu(C)^2 -> bf16 (He).  EPI=1: fp32 store (Ye).
template <int K, int N, int EPI>
__global__ void __launch_bounds__(256) gemm_kernel(const unsigned short* __restrict__ A,
                                                   const unsigned short* __restrict__ B,
                                                   unsigned short* __restrict__ Cbf,
                                                   float* __restrict__ Cf,
                                                   const int* __restrict__ ctrl) {
  const int e = blockIdx.z;
  const int cnt = ctrl[e];
  const int m0 = blockIdx.y * 128;
  if (m0 >= cnt) return;
  const int base = ctrl[8 + e];
  const int n0 = blockIdx.x * 128;

  __shared__ __align__(16) unsigned short ldsA[128 * 64];
  __shared__ __align__(16) unsigned short ldsB[128 * 64];

  const int tid = threadIdx.x;
  const int lane = tid & 63;
  const int wave = tid >> 6;
  const int wm = wave & 1, wn = wave >> 1;

  const unsigned short* Ae = A + (size_t)(base + m0) * K;
  const unsigned short* Be = B + ((size_t)e * N + n0) * (size_t)K;

  const int rsub = lane >> 3;   // row within 8-row chunk
  const int sg = lane & 7;      // stored 16B group (swizzled)

  floatx4 acc[4][4];
  floatx4 zero = {0.f, 0.f, 0.f, 0.f};
#pragma unroll
  for (int i = 0; i < 4; i++)
#pragma unroll
    for (int j = 0; j < 4; j++) acc[i][j] = zero;

  for (int k0 = 0; k0 < K; k0 += 64) {
#pragma unroll
    for (int j = 0; j < 4; j++) {
      int c = wave * 4 + j;
      int rc = c * 8 + rsub;
      int g = sg ^ (rc & 7);
      const unsigned short* ga = Ae + (size_t)rc * K + k0 + g * 8;
      const unsigned short* gb = Be + (size_t)rc * K + k0 + g * 8;
      __builtin_amdgcn_global_load_lds((const __attribute__((address_space(1))) unsigned int*)ga,
                                       (__attribute__((address_space(3))) unsigned int*)&ldsA[c * 512],
                                       16, 0, 0);
      __builtin_amdgcn_global_load_lds((const __attribute__((address_space(1))) unsigned int*)gb,
                                       (__attribute__((address_space(3))) unsigned int*)&ldsB[c * 512],
                                       16, 0, 0);
    }
    __builtin_amdgcn_s_waitcnt(0x0f70);  // vmcnt(0)
    __syncthreads();

#pragma unroll
    for (int kk = 0; kk < 2; kk++) {
      int q = lane >> 4;
      int gk = kk * 4 + q;
      short8 af[4], bfr[4];
#pragma unroll
      for (int mi = 0; mi < 4; mi++) {
        int row = wm * 64 + mi * 16 + (lane & 15);
        af[mi] = *(const short8*)&ldsA[row * 64 + (gk ^ (row & 7)) * 8];
      }
#pragma unroll
      for (int ni = 0; ni < 4; ni++) {
        int row = wn * 64 + ni * 16 + (lane & 15);
        bfr[ni] = *(const short8*)&ldsB[row * 64 + (gk ^ (row & 7)) * 8];
      }
#pragma unroll
      for (int mi = 0; mi < 4; mi++)
#pragma unroll
        for (int ni = 0; ni < 4; ni++)
          acc[mi][ni] = __builtin_amdgcn_mfma_f32_16x16x32_bf16(af[mi], bfr[ni], acc[mi][ni], 0, 0, 0);
    }
    __syncthreads();
  }

  // epilogue: D row=(lane>>4)*4+reg, col=lane&15
  // expert segments are packed back-to-back: mask stores past cnt.
  const int lm = lane >> 4;
  const int ln = lane & 15;
#pragma unroll
  for (int mi = 0; mi < 4; mi++) {
#pragma unroll
    for (int ni = 0; ni < 4; ni++) {
#pragma unroll
      for (int r = 0; r < 4; r++) {
        int row = m0 + wm * 64 + mi * 16 + lm * 4 + r;   // local row in expert segment
        if (row < cnt) {
          int col = n0 + wn * 64 + ni * 16 + ln;
          float v = acc[mi][ni][r];
          if (EPI == 0) {
            v = fmaxf(v, 0.f);
            v = v * v;
            Cbf[(size_t)(base + row) * N + col] = f2bf(v);
          } else {
            Cf[(size_t)(base + row) * N + col] = v;
          }
        }
      }
    }
  }
}

// ---------------- combine: out[t] = w0*Ye[p0] + w1*Ye[p1] --------------------
__global__ void __launch_bounds__(256) combine_kernel(const float* __restrict__ Ye,
                                                      const int* __restrict__ pos,
                                                      const float* __restrict__ wts,
                                                      float* __restrict__ out) {
  int t = blockIdx.x;
  int i = threadIdx.x;
  int p0 = pos[2 * t], p1 = pos[2 * t + 1];
  float w0 = wts[2 * t], w1 = wts[2 * t + 1];
  floatx4 y0 = ((const floatx4*)(Ye + (size_t)p0 * DIM))[i];
  floatx4 y1 = ((const floatx4*)(Ye + (size_t)p1 * DIM))[i];
  floatx4 o = y0 * w0 + y1 * w1;
  ((floatx4*)(out + (size_t)t * DIM))[i] = o;
  if (t == 0 && i == 0) out[(size_t)NTOK * DIM] = 0.f;  // aux_loss = 0
}

extern "C" void kernel_launch(void* const* d_in, const int* in_sizes, int n_in,
                              void* d_out, int out_size, void* d_ws, size_t ws_size,
                              hipStream_t stream) {
  const float* x   = (const float*)d_in[0];
  const float* Wr  = (const float*)d_in[1];
  const float* Wfc = (const float*)d_in[2];
  const float* Wpr = (const float*)d_in[3];
  float* out = (float*)d_out;
  char* ws = (char*)d_ws;

  const size_t WELEMS = (size_t)NEXP * HID * DIM;  // 16,777,216 per weight tensor

  int*   ctrl    = (int*)ws;                          // counts[8] bases[8] cursor[8]
  int*   experts = (int*)(ws + 128);                  // int2 per token
  int*   pos     = (int*)(ws + 128 + 16384);          // int2 per token
  float* wts     = (float*)(ws + 128 + 32768);        // float2 per token
  unsigned short* Wfcb = (unsigned short*)(ws + 65536);
  unsigned short* Wprb = Wfcb + WELEMS;
  unsigned short* Xe   = Wprb + WELEMS;               // [CAP x DIM] bf16
  unsigned short* He   = Xe + (size_t)CAP * DIM;      // [CAP x HID] bf16
  float*          Ye   = (float*)(He + (size_t)CAP * HID);  // [CAP x DIM] f32

  hipMemsetAsync(ws, 0, 128, stream);  // zero counts/bases/cursors

  pre_kernel<<<RB + 2 * CBT, 256, 0, stream>>>(x, Wr, Wfc, Wpr, Wfcb, Wprb, ctrl, experts, wts);
  scan_kernel<<<1, 64, 0, stream>>>(ctrl);
  gather_kernel<<<NTOK, 256, 0, stream>>>(x, ctrl, experts, pos, Xe);

  gemm_kernel<DIM, HID, 0><<<dim3(HID / 128, 16, NEXP), 256, 0, stream>>>(Xe, Wfcb, He, nullptr, ctrl);
  gemm_kernel<HID, DIM, 1><<<dim3(DIM / 128, 16, NEXP), 256, 0, stream>>>(He, Wprb, nullptr, Ye, ctrl);

  combine_kernel<<<NTOK, 256, 0, stream>>>(Ye, pos, wts, out);
}